// Round 12
// baseline (349.535 us; speedup 1.0000x reference)
//
#include <hip/hip_runtime.h>
#include <math.h>

#define LSEQ 8192
#define NFFT 8192       // half-size complex FFT via even/odd real packing
#define NT2 512
#define CCH 2048
#define TWO_PI 6.283185307179586f
#define PI_F  3.14159265358979323846f
#define KSTRIDE 8208    // float2 stride per channel in K workspace (>=8193)

// Twiddle-table layout in d_ws (float2 units)
#define T8OFF   0        // [idx=0..7][r=0..7]   : e^{-2pi i * idx*r/64}
#define T64OFF  64       // [idx=0..63][r=0..7]  : e^{-2pi i * idx*r/512}
#define T16OFF  1024     // [r=0..15][t=0..511]  : e^{-2pi i * t*r/8192}
#define TUOFF   9216     // [r=0..7][t=0..511]   : (cos,sin)(pi*(t+512r)/8192)
#define TBLTOT  16384    // table region size (float2)

// Parity-preserving XOR swizzle (verified conflict-free for all pass patterns).
__device__ __forceinline__ int SL2(int i) { return i ^ (((i >> 4) & 15) << 1); }

__device__ __forceinline__ float2 cmul(float2 a, float2 b) {
    return make_float2(fmaf(a.x, b.x, -a.y * b.y), fmaf(a.x, b.y, a.y * b.x));
}
__device__ __forceinline__ float2 conjf2(float2 a) { return make_float2(a.x, -a.y); }

// a * w for SGN<0 (tables store forward twiddles), a * conj(w) for SGN>0.
template<int SGN>
__device__ __forceinline__ float2 cmt(float2 a, float2 w) {
    if constexpr (SGN < 0)
        return make_float2(fmaf(a.x, w.x, -a.y * w.y), fmaf(a.x, w.y,  a.y * w.x));
    else
        return make_float2(fmaf(a.x, w.x,  a.y * w.y), fmaf(a.y, w.x, -a.x * w.y));
}

template<int SGN>
__device__ __forceinline__ void dft4(float2& a0, float2& a1, float2& a2, float2& a3) {
    float t0x = a0.x + a2.x, t0y = a0.y + a2.y;
    float t1x = a0.x - a2.x, t1y = a0.y - a2.y;
    float t2x = a1.x + a3.x, t2y = a1.y + a3.y;
    float t3x = a1.x - a3.x, t3y = a1.y - a3.y;
    float ux = (SGN < 0) ? t3y : -t3y;   // u = SGN*i*t3
    float uy = (SGN < 0) ? -t3x : t3x;
    a0 = make_float2(t0x + t2x, t0y + t2y);
    a1 = make_float2(t1x + ux, t1y + uy);
    a2 = make_float2(t0x - t2x, t0y - t2y);
    a3 = make_float2(t1x - ux, t1y - uy);
}

template<int SGN>
__device__ __forceinline__ void dft8(float2& v0, float2& v1, float2& v2, float2& v3,
                                     float2& v4, float2& v5, float2& v6, float2& v7) {
    float2 e0 = v0, e1 = v2, e2 = v4, e3 = v6;
    float2 o0 = v1, o1 = v3, o2 = v5, o3 = v7;
    dft4<SGN>(e0, e1, e2, e3);
    dft4<SGN>(o0, o1, o2, o3);
    const float sg = (float)SGN;
    const float H = 0.7071067811865476f;
    float2 t1 = cmul(o1, make_float2( H, sg * H));
    float2 t2 = make_float2(-sg * o2.y, sg * o2.x);
    float2 t3 = cmul(o3, make_float2(-H, sg * H));
    v0 = make_float2(e0.x + o0.x, e0.y + o0.y);
    v4 = make_float2(e0.x - o0.x, e0.y - o0.y);
    v1 = make_float2(e1.x + t1.x, e1.y + t1.y);
    v5 = make_float2(e1.x - t1.x, e1.y - t1.y);
    v2 = make_float2(e2.x + t2.x, e2.y + t2.y);
    v6 = make_float2(e2.x - t2.x, e2.y - t2.y);
    v3 = make_float2(e3.x + t3.x, e3.y + t3.y);
    v7 = make_float2(e3.x - t3.x, e3.y - t3.y);
}

// b128 paired LDS ops for logical elements {e, e+1} (e even).
__device__ __forceinline__ void rdp(const float2* ds, int e, float2& lo, float2& hi) {
    const float4 v = *reinterpret_cast<const float4*>(&ds[SL2(e)]);
    lo = make_float2(v.x, v.y);
    hi = make_float2(v.z, v.w);
}
__device__ __forceinline__ void wrp(float2* ds, int e, float2 lo, float2 hi) {
    *reinterpret_cast<float4*>(&ds[SL2(e)]) = make_float4(lo.x, lo.y, hi.x, hi.y);
}

// Radix-8 Stockham reads at stride NFFT/8 = 1024, butterflies {B_, B_+1}.
#define RD8X                                                                  \
    float2 a0,a1,a2,a3,a4,a5,a6,a7,b0,b1,b2,b3,b4,b5,b6,b7;                   \
    rdp(ds, B_,        a0, b0);                                               \
    rdp(ds, B_ + 1024, a1, b1);                                               \
    rdp(ds, B_ + 2048, a2, b2);                                               \
    rdp(ds, B_ + 3072, a3, b3);                                               \
    rdp(ds, B_ + 4096, a4, b4);                                               \
    rdp(ds, B_ + 5120, a5, b5);                                               \
    rdp(ds, B_ + 6144, a6, b6);                                               \
    rdp(ds, B_ + 7168, a7, b7);

#define DFT8AB(SGN)                                                           \
    dft8<(SGN)>(a0,a1,a2,a3,a4,a5,a6,a7);                                     \
    dft8<(SGN)>(b0,b1,b2,b3,b4,b5,b6,b7);

// Table-driven twiddles. Pair idx_a = B_ & (NS-1) starts at float2 offset
// idx_a*8 = float4 offset idx_a*4  (R11 bug was <<1: half the true offset).
#define TWID_TBL(SGN, NSv, TOFF) {                                            \
    const float4* tp_ = reinterpret_cast<const float4*>(tw + (TOFF)) +        \
                        ((B_ & ((NSv) - 1)) << 2);                            \
    const float4 q0_ = tp_[0], q1_ = tp_[1], q2_ = tp_[2], q3_ = tp_[3];      \
    const float4 q4_ = tp_[4], q5_ = tp_[5], q6_ = tp_[6], q7_ = tp_[7];      \
    a1 = cmt<(SGN)>(a1, make_float2(q0_.z, q0_.w));                           \
    a2 = cmt<(SGN)>(a2, make_float2(q1_.x, q1_.y));                           \
    a3 = cmt<(SGN)>(a3, make_float2(q1_.z, q1_.w));                           \
    a4 = cmt<(SGN)>(a4, make_float2(q2_.x, q2_.y));                           \
    a5 = cmt<(SGN)>(a5, make_float2(q2_.z, q2_.w));                           \
    a6 = cmt<(SGN)>(a6, make_float2(q3_.x, q3_.y));                           \
    a7 = cmt<(SGN)>(a7, make_float2(q3_.z, q3_.w));                           \
    b1 = cmt<(SGN)>(b1, make_float2(q4_.z, q4_.w));                           \
    b2 = cmt<(SGN)>(b2, make_float2(q5_.x, q5_.y));                           \
    b3 = cmt<(SGN)>(b3, make_float2(q5_.z, q5_.w));                           \
    b4 = cmt<(SGN)>(b4, make_float2(q6_.x, q6_.y));                           \
    b5 = cmt<(SGN)>(b5, make_float2(q6_.z, q6_.w));                           \
    b6 = cmt<(SGN)>(b6, make_float2(q7_.x, q7_.y));                           \
    b7 = cmt<(SGN)>(b7, make_float2(q7_.z, q7_.w));                           \
}

#define WR8P(NSv) {                                                           \
    const int i_ = B_ & ((NSv) - 1);                                          \
    const int d_ = ((B_ - i_) << 3) + i_;                                     \
    wrp(ds, d_,             a0, b0);                                          \
    wrp(ds, d_ +     (NSv), a1, b1);                                          \
    wrp(ds, d_ + 2 * (NSv), a2, b2);                                          \
    wrp(ds, d_ + 3 * (NSv), a3, b3);                                          \
    wrp(ds, d_ + 4 * (NSv), a4, b4);                                          \
    wrp(ds, d_ + 5 * (NSv), a5, b5);                                          \
    wrp(ds, d_ + 6 * (NSv), a6, b6);                                          \
    wrp(ds, d_ + 7 * (NSv), a7, b7);                                          \
}

#define WR8SEQ {                                                              \
    const int d_ = B_ << 3;                                                   \
    wrp(ds, d_,      a0, a1);                                                 \
    wrp(ds, d_ +  2, a2, a3);                                                 \
    wrp(ds, d_ +  4, a4, a5);                                                 \
    wrp(ds, d_ +  6, a6, a7);                                                 \
    wrp(ds, d_ +  8, b0, b1);                                                 \
    wrp(ds, d_ + 10, b2, b3);                                                 \
    wrp(ds, d_ + 12, b4, b5);                                                 \
    wrp(ds, d_ + 14, b6, b7);                                                 \
}

#define P8MID(SGN, NSv, TOFF) {                                               \
    RD8X                                                                      \
    TWID_TBL(SGN, NSv, TOFF)                                                  \
    DFT8AB(SGN)                                                               \
    __syncthreads();                                                          \
    WR8P(NSv)                                                                 \
    __syncthreads();                                                          \
}

#define P8FIRST_LDS(SGN) {                                                    \
    RD8X                                                                      \
    DFT8AB(SGN)                                                               \
    __syncthreads();                                                          \
    WR8SEQ                                                                    \
    __syncthreads();                                                          \
}

// Radix-16 DFT over named float2 scalars; X[k] ends in P{4*(k&3)+(k>>2)}.
#define DFT16M(SGN, P) {                                                            \
    dft4<(SGN)>(P##0, P##4, P##8,  P##12);                                          \
    dft4<(SGN)>(P##1, P##5, P##9,  P##13);                                          \
    dft4<(SGN)>(P##2, P##6, P##10, P##14);                                          \
    dft4<(SGN)>(P##3, P##7, P##11, P##15);                                          \
    const float sg_ = (float)(SGN);                                                 \
    const float2 tw1_ = make_float2( 0.9238795325112867f,  sg_ * 0.3826834323650898f); \
    const float2 tw2_ = make_float2( 0.7071067811865476f,  sg_ * 0.7071067811865476f); \
    const float2 tw3_ = make_float2( 0.3826834323650898f,  sg_ * 0.9238795325112867f); \
    const float2 tw6_ = make_float2(-0.7071067811865476f,  sg_ * 0.7071067811865476f); \
    const float2 tw9_ = make_float2(-0.9238795325112867f, -sg_ * 0.3826834323650898f); \
    P##5  = cmul(P##5,  tw1_);                                                      \
    P##6  = cmul(P##6,  tw2_);                                                      \
    P##7  = cmul(P##7,  tw3_);                                                      \
    P##9  = cmul(P##9,  tw2_);                                                      \
    P##10 = make_float2(-sg_ * (P##10).y, sg_ * (P##10).x);                         \
    P##11 = cmul(P##11, tw6_);                                                      \
    P##13 = cmul(P##13, tw3_);                                                      \
    P##14 = cmul(P##14, tw6_);                                                      \
    P##15 = cmul(P##15, tw9_);                                                      \
    dft4<(SGN)>(P##0,  P##1,  P##2,  P##3);                                         \
    dft4<(SGN)>(P##4,  P##5,  P##6,  P##7);                                         \
    dft4<(SGN)>(P##8,  P##9,  P##10, P##11);                                        \
    dft4<(SGN)>(P##12, P##13, P##14, P##15);                                        \
}

// Final radix-16 pass (NS=512): class {tid+512r}; twiddles from T16 (coalesced).
#define R16_LOAD_TWIDDLE(SGN)                                                 \
    const float2* t16_ = tw + T16OFF;                                         \
    float2 m0  = ds[SL2(tid)];                                                \
    float2 m1  = ds[SL2(tid +  512)];                                         \
    float2 m2  = ds[SL2(tid + 1024)];                                         \
    float2 m3  = ds[SL2(tid + 1536)];                                         \
    float2 m4  = ds[SL2(tid + 2048)];                                         \
    float2 m5  = ds[SL2(tid + 2560)];                                         \
    float2 m6  = ds[SL2(tid + 3072)];                                         \
    float2 m7  = ds[SL2(tid + 3584)];                                         \
    float2 m8  = ds[SL2(tid + 4096)];                                         \
    float2 m9  = ds[SL2(tid + 4608)];                                         \
    float2 m10 = ds[SL2(tid + 5120)];                                         \
    float2 m11 = ds[SL2(tid + 5632)];                                         \
    float2 m12 = ds[SL2(tid + 6144)];                                         \
    float2 m13 = ds[SL2(tid + 6656)];                                         \
    float2 m14 = ds[SL2(tid + 7168)];                                         \
    float2 m15 = ds[SL2(tid + 7680)];                                         \
    m1  = cmt<(SGN)>(m1,  t16_[ 1 * 512 + tid]);                              \
    m2  = cmt<(SGN)>(m2,  t16_[ 2 * 512 + tid]);                              \
    m3  = cmt<(SGN)>(m3,  t16_[ 3 * 512 + tid]);                              \
    m4  = cmt<(SGN)>(m4,  t16_[ 4 * 512 + tid]);                              \
    m5  = cmt<(SGN)>(m5,  t16_[ 5 * 512 + tid]);                              \
    m6  = cmt<(SGN)>(m6,  t16_[ 6 * 512 + tid]);                              \
    m7  = cmt<(SGN)>(m7,  t16_[ 7 * 512 + tid]);                              \
    m8  = cmt<(SGN)>(m8,  t16_[ 8 * 512 + tid]);                              \
    m9  = cmt<(SGN)>(m9,  t16_[ 9 * 512 + tid]);                              \
    m10 = cmt<(SGN)>(m10, t16_[10 * 512 + tid]);                              \
    m11 = cmt<(SGN)>(m11, t16_[11 * 512 + tid]);                              \
    m12 = cmt<(SGN)>(m12, t16_[12 * 512 + tid]);                              \
    m13 = cmt<(SGN)>(m13, t16_[13 * 512 + tid]);                              \
    m14 = cmt<(SGN)>(m14, t16_[14 * 512 + tid]);                              \
    m15 = cmt<(SGN)>(m15, t16_[15 * 512 + tid]);

// Natural-order write-back of r16 outputs (slot tid+512k <- m{4*(k&3)+(k>>2)}).
#define R16_STORE_LDS                                                         \
    ds[SL2(tid)]        = m0;                                                 \
    ds[SL2(tid +  512)] = m4;                                                 \
    ds[SL2(tid + 1024)] = m8;                                                 \
    ds[SL2(tid + 1536)] = m12;                                                \
    ds[SL2(tid + 2048)] = m1;                                                 \
    ds[SL2(tid + 2560)] = m5;                                                 \
    ds[SL2(tid + 3072)] = m9;                                                 \
    ds[SL2(tid + 3584)] = m13;                                                \
    ds[SL2(tid + 4096)] = m2;                                                 \
    ds[SL2(tid + 4608)] = m6;                                                 \
    ds[SL2(tid + 5120)] = m10;                                                \
    ds[SL2(tid + 5632)] = m14;                                                \
    ds[SL2(tid + 6144)] = m3;                                                 \
    ds[SL2(tid + 6656)] = m7;                                                 \
    ds[SL2(tid + 7168)] = m11;                                                \
    ds[SL2(tid + 7680)] = m15;

// ================= Setup: twiddle tables (double-precision sincos) =================
__global__ __launch_bounds__(256)
void hyena_tables(float2* __restrict__ tw)
{
    const int i = blockIdx.x * 256 + threadIdx.x;     // 0..16383
    if (i >= TBLTOT) return;
    double ang = 0.0;
    if (i < 64) {                                     // T8 [idx][r]
        const int idx = i >> 3, r = i & 7;
        ang = -6.283185307179586476925286766559 * (double)(idx * r) / 64.0;
    } else if (i < 576) {                             // T64 [idx][r]
        const int i2 = i - 64;
        const int idx = i2 >> 3, r = i2 & 7;
        ang = -6.283185307179586476925286766559 * (double)(idx * r) / 512.0;
    } else if (i >= T16OFF && i < T16OFF + 8192) {    // T16 [r][t]
        const int i2 = i - T16OFF;
        const int r = i2 >> 9, t = i2 & 511;
        ang = -6.283185307179586476925286766559 * (double)(t * r) / 8192.0;
    } else if (i >= TUOFF && i < TUOFF + 4096) {      // TU [r][t]
        const int i2 = i - TUOFF;
        const int r = i2 >> 9, t = i2 & 511;
        ang = 3.1415926535897932384626433832795 * (double)(t + 512 * r) / 8192.0;
    } else {
        tw[i] = make_float2(1.f, 0.f);
        return;
    }
    double s, c;
    sincos(ang, &s, &c);
    tw[i] = make_float2((float)c, (float)s);
}

// ================= Kernel A: K half-spectrum (16384 rfft) -> workspace =================
__global__ __launch_bounds__(NT2)
void hyena_kfft8(const float* __restrict__ k, const float* __restrict__ bias,
                 float2* __restrict__ kw, const float2* __restrict__ tw)
{
    __shared__ alignas(16) float2 ds[NFFT];           // 64 KiB -> 2 blocks/CU
    const int c = blockIdx.x, tid = threadIdx.x;
    const int B_ = tid << 1;
    const float* kp = k + (size_t)c * LSEQ;
    const float bsv = bias[c];

    {   // pass0 (NS=1): w[e] = k[2e] + i*k[2e+1]; e >= 4096 is zero padding.
        float2 a0,a1,a2,a3,a4,a5,a6,a7,b0,b1,b2,b3,b4,b5,b6,b7;
        float4 v;
        v = *(const float4*)&kp[(B_ << 1)];
        a0 = make_float2(v.x, v.y); b0 = make_float2(v.z, v.w);
        if (tid == 0) a0.x += bsv;                    // bias = conv tap s=0
        v = *(const float4*)&kp[(B_ << 1) + 2048];
        a1 = make_float2(v.x, v.y); b1 = make_float2(v.z, v.w);
        v = *(const float4*)&kp[(B_ << 1) + 4096];
        a2 = make_float2(v.x, v.y); b2 = make_float2(v.z, v.w);
        v = *(const float4*)&kp[(B_ << 1) + 6144];
        a3 = make_float2(v.x, v.y); b3 = make_float2(v.z, v.w);
        a4 = a5 = a6 = a7 = b4 = b5 = b6 = b7 = make_float2(0.f, 0.f);
        DFT8AB(-1)
        WR8SEQ
        __syncthreads();
    }
    P8MID(-1, 8,  T8OFF)
    P8MID(-1, 64, T64OFF)
    {   // final radix-16 (NS=512), in place (class-local).
        R16_LOAD_TWIDDLE(-1)
        DFT16M(-1, m)
        R16_STORE_LDS
    }
    __syncthreads();

    // Untangle to K[j] = rfft16384(k)[j] * (1/16384), j = 0..8192.
    {
        const float sc = 1.0f / 16384.0f;
        const float2* tu = tw + TUOFF;
        float2* kc = kw + (size_t)c * KSTRIDE;
#pragma unroll
        for (int r = 0; r < 8; r++) {
            const int j = tid + (r << 9);
            if (j == 0) {
                float2 W0 = ds[SL2(0)];
                kc[0]    = make_float2((W0.x + W0.y) * sc, 0.f);
                kc[8192] = make_float2((W0.x - W0.y) * sc, 0.f);
                float2 W4 = ds[SL2(4096)];
                kc[4096] = make_float2(W4.x * sc, -W4.y * sc);   // conj(W)*sc
            } else {
                const int jm = NFFT - j;
                float2 Wj = ds[SL2(j)];
                float2 Wm = ds[SL2(jm)];
                float Ex = 0.5f * (Wj.x + Wm.x), Ey = 0.5f * (Wj.y - Wm.y);
                float Dx = 0.5f * (Wj.x - Wm.x), Dy = 0.5f * (Wj.y + Wm.y);
                float Ox = Dy, Oy = -Dx;                         // O = -i*D
                const float2 cs = tu[(r << 9) + tid];
                const float c_ = cs.x, s_ = cs.y;
                float2 tO = cmul(make_float2(c_, -s_), make_float2(Ox, Oy));
                float2 uO = cmul(make_float2(c_,  s_), make_float2(Ox, -Oy));
                kc[j]  = make_float2((Ex + tO.x) * sc, ( Ey + tO.y) * sc);
                kc[jm] = make_float2((Ex - uO.x) * sc, (-Ey - uO.y) * sc);
            }
        }
    }
}

// ====== Kernel B: per (b,c): W=FFT(x even/odd) -> untangle*K*tangle -> IFFT -> y ======
__global__ __launch_bounds__(NT2)
void hyena_xconv8(const float* __restrict__ x, const float2* __restrict__ kw,
                  float* __restrict__ y, const float2* __restrict__ tw)
{
    __shared__ alignas(16) float2 ds[NFFT];           // 64 KiB -> 2 blocks/CU
    const int bid = blockIdx.x, tid = threadIdx.x;
    const int c = bid >> 1, b = bid & 1;              // adjacent blocks share K row
    const int B_ = tid << 1;
    const float* xp = x + ((size_t)(b * CCH + c)) * LSEQ;
    float*       yp = y + ((size_t)(b * CCH + c)) * LSEQ;

    {   // forward pass0: w[e] = x[2e] + i*x[2e+1]; e >= 4096 zero.
        float2 a0,a1,a2,a3,a4,a5,a6,a7,b0,b1,b2,b3,b4,b5,b6,b7;
        float4 v;
        v = *(const float4*)&xp[(B_ << 1)];
        a0 = make_float2(v.x, v.y); b0 = make_float2(v.z, v.w);
        v = *(const float4*)&xp[(B_ << 1) + 2048];
        a1 = make_float2(v.x, v.y); b1 = make_float2(v.z, v.w);
        v = *(const float4*)&xp[(B_ << 1) + 4096];
        a2 = make_float2(v.x, v.y); b2 = make_float2(v.z, v.w);
        v = *(const float4*)&xp[(B_ << 1) + 6144];
        a3 = make_float2(v.x, v.y); b3 = make_float2(v.z, v.w);
        a4 = a5 = a6 = a7 = b4 = b5 = b6 = b7 = make_float2(0.f, 0.f);
        DFT8AB(-1)
        WR8SEQ
        __syncthreads();
    }
    P8MID(-1, 8,  T8OFF)
    P8MID(-1, 64, T64OFF)
    {   // final radix-16 forward, in place.
        R16_LOAD_TWIDDLE(-1)
        DFT16M(-1, m)
        R16_STORE_LDS
    }
    __syncthreads();

    // Untangle X, multiply by K, tangle to V (pairs (j, N-j) owned per thread).
    {
        const float2* kc = kw + (size_t)c * KSTRIDE;
        const float2* tu = tw + TUOFF;
#pragma unroll
        for (int r = 0; r < 8; r++) {
            const int j = tid + (r << 9);
            if (j == 0) {
                float2 W0 = ds[SL2(0)];
                float X0 = W0.x + W0.y, XN = W0.x - W0.y;
                float2 K0 = kc[0], KN = kc[8192];
                float2 Z0 = make_float2(X0 * K0.x, X0 * K0.y);
                float2 ZN = make_float2(XN * KN.x, XN * KN.y);
                ds[SL2(0)] = make_float2(Z0.x + ZN.x - (Z0.y - ZN.y),
                                         Z0.y + ZN.y + (Z0.x - ZN.x));
                float2 W4 = ds[SL2(4096)];
                float2 Z4 = cmul(conjf2(W4), kc[4096]);
                ds[SL2(4096)] = make_float2(2.f * Z4.x, -2.f * Z4.y);
            } else {
                const int jm = NFFT - j;
                float2 Wj = ds[SL2(j)];
                float2 Wm = ds[SL2(jm)];
                float Ex = 0.5f * (Wj.x + Wm.x), Ey = 0.5f * (Wj.y - Wm.y);
                float Dx = 0.5f * (Wj.x - Wm.x), Dy = 0.5f * (Wj.y + Wm.y);
                float Ox = Dy, Oy = -Dx;
                const float2 cs = tu[(r << 9) + tid];
                const float c_ = cs.x, s_ = cs.y;
                float2 tO = cmul(make_float2(c_, -s_), make_float2(Ox, Oy));
                float2 Xj = make_float2(Ex + tO.x,  Ey + tO.y);
                float2 uO = cmul(make_float2(c_,  s_), make_float2(Ox, -Oy));
                float2 Xm = make_float2(Ex - uO.x, -Ey - uO.y);
                float2 Zj = cmul(Xj, kc[j]);
                float2 Zm = cmul(Xm, kc[jm]);
                // V[j] = (Zj + conj Zm) + i e^{i pi j/N} (Zj - conj Zm)
                float2 P = make_float2(Zj.x + Zm.x, Zj.y - Zm.y);
                float2 Q = make_float2(Zj.x - Zm.x, Zj.y + Zm.y);
                float2 Vj = make_float2(P.x - s_ * Q.x - c_ * Q.y,
                                        P.y - s_ * Q.y + c_ * Q.x);
                float2 P2 = make_float2(Zm.x + Zj.x, Zm.y - Zj.y);
                float2 Q2 = make_float2(Zm.x - Zj.x, Zm.y + Zj.y);
                float2 Vm = make_float2(P2.x - s_ * Q2.x + c_ * Q2.y,
                                        P2.y - s_ * Q2.y - c_ * Q2.x);
                ds[SL2(j)]  = Vj;
                ds[SL2(jm)] = Vm;
            }
        }
    }
    __syncthreads();

    // Inverse FFT (unscaled; scaling folded into K).
    P8FIRST_LDS(1)
    P8MID(1, 8,  T8OFF)
    P8MID(1, 64, T64OFF)
    {   // final inverse radix-16: v[n] for n < 4096 only -> y[2n], y[2n+1].
        R16_LOAD_TWIDDLE(1)
        DFT16M(1, m)
        *(float2*)&yp[(tid) << 1]          = m0;
        *(float2*)&yp[(tid +  512) << 1]   = m4;
        *(float2*)&yp[(tid + 1024) << 1]   = m8;
        *(float2*)&yp[(tid + 1536) << 1]   = m12;
        *(float2*)&yp[(tid + 2048) << 1]   = m1;
        *(float2*)&yp[(tid + 2560) << 1]   = m5;
        *(float2*)&yp[(tid + 3072) << 1]   = m9;
        *(float2*)&yp[(tid + 3584) << 1]   = m13;
    }
}

extern "C" void kernel_launch(void* const* d_in, const int* in_sizes, int n_in,
                              void* d_out, int out_size, void* d_ws, size_t ws_size,
                              hipStream_t stream) {
    const float* x    = (const float*)d_in[0];
    const float* k    = (const float*)d_in[1];
    const float* bias = (const float*)d_in[2];
    float* y          = (float*)d_out;

    float2* tw = (float2*)d_ws;              // table region: TBLTOT float2 (128 KiB)
    float2* kw = tw + TBLTOT;                // K spectra: 2048 * KSTRIDE float2

    hyena_tables<<<dim3((TBLTOT + 255) / 256), dim3(256), 0, stream>>>(tw);
    hyena_kfft8 <<<dim3(CCH),     dim3(NT2), 0, stream>>>(k, bias, kw, tw);
    hyena_xconv8<<<dim3(2 * CCH), dim3(NT2), 0, stream>>>(x, kw, y, tw);
}

// Round 13
// 182.224 us; speedup vs baseline: 1.9182x; 1.9182x over previous
//
#include <hip/hip_runtime.h>

#define LSEQ 8192
#define NFFT 8192       // half-size complex FFT via even/odd real packing
#define NT2 512
#define CCH 2048
#define TWO_PI 6.283185307179586f
#define PI_F  3.14159265358979323846f
#define KSTRIDE 8208    // float2 stride per channel in K workspace (>=8193)

// Parity-preserving XOR swizzle. Key identity used for hoisting:
// SL2(i + 512*r) == SL2(i) + 512*r  (512r doesn't touch source bits[7:4],
// and the XOR targets bits[4:1] which 512r can't carry into).
__device__ __forceinline__ int SL2(int i) { return i ^ (((i >> 4) & 15) << 1); }

__device__ __forceinline__ float2 cmul(float2 a, float2 b) {
    return b * a.x + make_float2(-b.y, b.x) * a.y;   // fma-contracted by compiler
}
__device__ __forceinline__ float2 conjf2(float2 a) { return make_float2(a.x, -a.y); }

template<int SGN>
__device__ __forceinline__ float2 muli(float2 t) {   // SGN * i * t
    return (SGN < 0) ? make_float2(t.y, -t.x) : make_float2(-t.y, t.x);
}

template<int SGN>
__device__ __forceinline__ void dft4(float2& a0, float2& a1, float2& a2, float2& a3) {
    float2 t0 = a0 + a2, t1 = a0 - a2, t2 = a1 + a3, t3 = a1 - a3;
    float2 u = muli<SGN>(t3);
    a0 = t0 + t2; a1 = t1 + u; a2 = t0 - t2; a3 = t1 - u;
}

template<int SGN>
__device__ __forceinline__ void dft8(float2& v0, float2& v1, float2& v2, float2& v3,
                                     float2& v4, float2& v5, float2& v6, float2& v7) {
    float2 e0 = v0, e1 = v2, e2 = v4, e3 = v6;
    float2 o0 = v1, o1 = v3, o2 = v5, o3 = v7;
    dft4<SGN>(e0, e1, e2, e3);
    dft4<SGN>(o0, o1, o2, o3);
    const float sg = (float)SGN;
    const float H = 0.7071067811865476f;
    float2 t1 = cmul(o1, make_float2( H, sg * H));
    float2 t2 = muli<SGN>(o2);
    float2 t3 = cmul(o3, make_float2(-H, sg * H));
    v0 = e0 + o0; v4 = e0 - o0;
    v1 = e1 + t1; v5 = e1 - t1;
    v2 = e2 + t2; v6 = e2 - t2;
    v3 = e3 + t3; v7 = e3 - t3;
}

// Raw b128 paired LDS access (caller supplies swizzled pointer).
__device__ __forceinline__ void rdr(const float2* p, float2& lo, float2& hi) {
    const float4 v = *reinterpret_cast<const float4*>(p);
    lo = make_float2(v.x, v.y);
    hi = make_float2(v.z, v.w);
}
__device__ __forceinline__ void wrr(float2* p, float2 lo, float2 hi) {
    *reinterpret_cast<float4*>(p) = make_float4(lo.x, lo.y, hi.x, hi.y);
}
// Swizzling paired write (scatter patterns where hoisting is invalid).
__device__ __forceinline__ void wrp(float2* ds, int e, float2 lo, float2 hi) {
    wrr(&ds[SL2(e)], lo, hi);
}

// Radix-8 Stockham reads at stride 1024: swizzled base + offset immediates.
#define RD8X                                                                  \
    float2 a0,a1,a2,a3,a4,a5,a6,a7,b0,b1,b2,b3,b4,b5,b6,b7;                   \
    {   const float2* p_ = ds + SL2(B_);                                      \
        rdr(p_,        a0, b0);                                               \
        rdr(p_ + 1024, a1, b1);                                               \
        rdr(p_ + 2048, a2, b2);                                               \
        rdr(p_ + 3072, a3, b3);                                               \
        rdr(p_ + 4096, a4, b4);                                               \
        rdr(p_ + 5120, a5, b5);                                               \
        rdr(p_ + 6144, a6, b6);                                               \
        rdr(p_ + 7168, a7, b7);                                               \
    }

#define DFT8AB(SGN)                                                           \
    dft8<(SGN)>(a0,a1,a2,a3,a4,a5,a6,a7);                                     \
    dft8<(SGN)>(b0,b1,b2,b3,b4,b5,b6,b7);

// One sincos; squaring-tree powers (depth<=3, <=4 live w's); wb = wa * wD.
#define TWID(SGN, NSv, WDC, WDS) {                                            \
    float s_, c_;                                                             \
    __sincosf((float)(SGN) * TWO_PI / (float)((NSv) * 8) *                    \
              (float)(B_ & ((NSv) - 1)), &s_, &c_);                           \
    const float2 w1a = make_float2(c_, s_);                                   \
    a1 = cmul(a1, w1a);                                                       \
    const float2 w2a = cmul(w1a, w1a);                                        \
    a2 = cmul(a2, w2a);                                                       \
    const float2 w3a = cmul(w2a, w1a);                                        \
    a3 = cmul(a3, w3a);                                                       \
    const float2 w4a = cmul(w2a, w2a);                                        \
    a4 = cmul(a4, w4a);                                                       \
    a5 = cmul(a5, cmul(w3a, w2a));                                            \
    a6 = cmul(a6, cmul(w3a, w3a));                                            \
    a7 = cmul(a7, cmul(w4a, w3a));                                            \
    const float2 w1b = cmul(w1a, make_float2((WDC), (float)(SGN) * (WDS)));   \
    b1 = cmul(b1, w1b);                                                       \
    const float2 w2b = cmul(w1b, w1b);                                        \
    b2 = cmul(b2, w2b);                                                       \
    const float2 w3b = cmul(w2b, w1b);                                        \
    b3 = cmul(b3, w3b);                                                       \
    const float2 w4b = cmul(w2b, w2b);                                        \
    b4 = cmul(b4, w4b);                                                       \
    b5 = cmul(b5, cmul(w3b, w2b));                                            \
    b6 = cmul(b6, cmul(w3b, w3b));                                            \
    b7 = cmul(b7, cmul(w4b, w3b));                                            \
}

// Stockham scatter (swizzle per access: offsets touch swizzle source bits).
#define WR8P(NSv) {                                                           \
    const int i_ = B_ & ((NSv) - 1);                                          \
    const int d_ = ((B_ - i_) << 3) + i_;                                     \
    wrp(ds, d_,             a0, b0);                                          \
    wrp(ds, d_ +     (NSv), a1, b1);                                          \
    wrp(ds, d_ + 2 * (NSv), a2, b2);                                          \
    wrp(ds, d_ + 3 * (NSv), a3, b3);                                          \
    wrp(ds, d_ + 4 * (NSv), a4, b4);                                          \
    wrp(ds, d_ + 5 * (NSv), a5, b5);                                          \
    wrp(ds, d_ + 6 * (NSv), a6, b6);                                          \
    wrp(ds, d_ + 7 * (NSv), a7, b7);                                          \
}

#define WR8SEQ {                                                              \
    const int d_ = B_ << 3;                                                   \
    wrp(ds, d_,      a0, a1);                                                 \
    wrp(ds, d_ +  2, a2, a3);                                                 \
    wrp(ds, d_ +  4, a4, a5);                                                 \
    wrp(ds, d_ +  6, a6, a7);                                                 \
    wrp(ds, d_ +  8, b0, b1);                                                 \
    wrp(ds, d_ + 10, b2, b3);                                                 \
    wrp(ds, d_ + 12, b4, b5);                                                 \
    wrp(ds, d_ + 14, b6, b7);                                                 \
}

#define P8MID(SGN, NSv, WDC, WDS) {                                           \
    RD8X                                                                      \
    TWID(SGN, NSv, WDC, WDS)                                                  \
    DFT8AB(SGN)                                                               \
    __syncthreads();                                                          \
    WR8P(NSv)                                                                 \
    __syncthreads();                                                          \
}

#define P8FIRST_LDS(SGN) {                                                    \
    RD8X                                                                      \
    DFT8AB(SGN)                                                               \
    __syncthreads();                                                          \
    WR8SEQ                                                                    \
    __syncthreads();                                                          \
}

// wD = e^{2pi/(8*NS)} for NS = 8 / 64.
#define WD8C  0.9951847266721969f
#define WD8S  0.0980171403295606f
#define WD64C 0.9999247018391445f
#define WD64S 0.012271538285719925f

// Radix-16 DFT over named float2 scalars; X[k] ends in P{4*(k&3)+(k>>2)}.
#define DFT16M(SGN, P) {                                                            \
    dft4<(SGN)>(P##0, P##4, P##8,  P##12);                                          \
    dft4<(SGN)>(P##1, P##5, P##9,  P##13);                                          \
    dft4<(SGN)>(P##2, P##6, P##10, P##14);                                          \
    dft4<(SGN)>(P##3, P##7, P##11, P##15);                                          \
    const float sg_ = (float)(SGN);                                                 \
    const float2 tw1_ = make_float2( 0.9238795325112867f,  sg_ * 0.3826834323650898f); \
    const float2 tw2_ = make_float2( 0.7071067811865476f,  sg_ * 0.7071067811865476f); \
    const float2 tw3_ = make_float2( 0.3826834323650898f,  sg_ * 0.9238795325112867f); \
    const float2 tw6_ = make_float2(-0.7071067811865476f,  sg_ * 0.7071067811865476f); \
    const float2 tw9_ = make_float2(-0.9238795325112867f, -sg_ * 0.3826834323650898f); \
    P##5  = cmul(P##5,  tw1_);                                                      \
    P##6  = cmul(P##6,  tw2_);                                                      \
    P##7  = cmul(P##7,  tw3_);                                                      \
    P##9  = cmul(P##9,  tw2_);                                                      \
    P##10 = muli<(SGN)>(P##10);                                                     \
    P##11 = cmul(P##11, tw6_);                                                      \
    P##13 = cmul(P##13, tw3_);                                                      \
    P##14 = cmul(P##14, tw6_);                                                      \
    P##15 = cmul(P##15, tw9_);                                                      \
    dft4<(SGN)>(P##0,  P##1,  P##2,  P##3);                                         \
    dft4<(SGN)>(P##4,  P##5,  P##6,  P##7);                                         \
    dft4<(SGN)>(P##8,  P##9,  P##10, P##11);                                        \
    dft4<(SGN)>(P##12, P##13, P##14, P##15);                                        \
}

// Final radix-16 pass loads (hoisted swizzle base) + twiddle squaring tree.
#define R16_LOAD_TWIDDLE(SGN)                                                 \
    float2 m0,m1,m2,m3,m4,m5,m6,m7,m8,m9,m10,m11,m12,m13,m14,m15;             \
    {   const float2* p_ = ds + SL2(tid);                                     \
        m0  = p_[0];    m1  = p_[512];  m2  = p_[1024]; m3  = p_[1536];       \
        m4  = p_[2048]; m5  = p_[2560]; m6  = p_[3072]; m7  = p_[3584];       \
        m8  = p_[4096]; m9  = p_[4608]; m10 = p_[5120]; m11 = p_[5632];       \
        m12 = p_[6144]; m13 = p_[6656]; m14 = p_[7168]; m15 = p_[7680];       \
    }                                                                         \
    {   float s_, c_;                                                         \
        __sincosf((float)(SGN) * TWO_PI / 8192.0f * (float)tid, &s_, &c_);    \
        const float2 w1 = make_float2(c_, s_);                                \
        m1 = cmul(m1, w1);                                                    \
        const float2 w2 = cmul(w1, w1);   m2  = cmul(m2,  w2);                \
        const float2 w3 = cmul(w2, w1);   m3  = cmul(m3,  w3);                \
        const float2 w4 = cmul(w2, w2);   m4  = cmul(m4,  w4);                \
        const float2 w5 = cmul(w3, w2);   m5  = cmul(m5,  w5);                \
        const float2 w6 = cmul(w3, w3);   m6  = cmul(m6,  w6);                \
        const float2 w7 = cmul(w4, w3);   m7  = cmul(m7,  w7);                \
        const float2 w8 = cmul(w4, w4);   m8  = cmul(m8,  w8);                \
        m9  = cmul(m9,  cmul(w5, w4));                                        \
        m10 = cmul(m10, cmul(w5, w5));                                        \
        m11 = cmul(m11, cmul(w6, w5));                                        \
        m12 = cmul(m12, cmul(w6, w6));                                        \
        m13 = cmul(m13, cmul(w7, w6));                                        \
        m14 = cmul(m14, cmul(w7, w7));                                        \
        m15 = cmul(m15, cmul(w8, w7));                                        \
    }

// Natural-order write-back (hoisted base; slot tid+512k <- m{4*(k&3)+(k>>2)}).
#define R16_STORE_LDS {                                                       \
    float2* p_ = ds + SL2(tid);                                               \
    p_[0]    = m0;  p_[512]  = m4;  p_[1024] = m8;  p_[1536] = m12;           \
    p_[2048] = m1;  p_[2560] = m5;  p_[3072] = m9;  p_[3584] = m13;           \
    p_[4096] = m2;  p_[4608] = m6;  p_[5120] = m10; p_[5632] = m14;           \
    p_[6144] = m3;  p_[6656] = m7;  p_[7168] = m11; p_[7680] = m15;           \
}

// Untangle rotation step: e^{i*pi/16}.
#define UE1 make_float2(0.9807852804032304f, 0.1950903220161283f)

// ================= Kernel A: K half-spectrum (16384 rfft) -> workspace =================
__global__ __launch_bounds__(NT2)
void hyena_kfft8(const float* __restrict__ k, const float* __restrict__ bias,
                 float2* __restrict__ kw)
{
    __shared__ alignas(16) float2 ds[NFFT];           // 64 KiB -> 2 blocks/CU
    const int c = blockIdx.x, tid = threadIdx.x;
    const int B_ = tid << 1;
    const float* kp = k + (size_t)c * LSEQ;
    const float bsv = bias[c];

    {   // pass0 (NS=1): w[e] = k[2e] + i*k[2e+1]; e >= 4096 is zero padding.
        float2 a0,a1,a2,a3,a4,a5,a6,a7,b0,b1,b2,b3,b4,b5,b6,b7;
        float4 v;
        v = *(const float4*)&kp[(B_ << 1)];
        a0 = make_float2(v.x, v.y); b0 = make_float2(v.z, v.w);
        if (tid == 0) a0.x += bsv;                    // bias = conv tap s=0
        v = *(const float4*)&kp[(B_ << 1) + 2048];
        a1 = make_float2(v.x, v.y); b1 = make_float2(v.z, v.w);
        v = *(const float4*)&kp[(B_ << 1) + 4096];
        a2 = make_float2(v.x, v.y); b2 = make_float2(v.z, v.w);
        v = *(const float4*)&kp[(B_ << 1) + 6144];
        a3 = make_float2(v.x, v.y); b3 = make_float2(v.z, v.w);
        a4 = a5 = a6 = a7 = b4 = b5 = b6 = b7 = make_float2(0.f, 0.f);
        DFT8AB(-1)
        WR8SEQ
        __syncthreads();
    }
    P8MID(-1, 8,  WD8C,  WD8S)
    P8MID(-1, 64, WD64C, WD64S)
    {   // final radix-16 (NS=512), in place (class-local).
        R16_LOAD_TWIDDLE(-1)
        DFT16M(-1, m)
        R16_STORE_LDS
    }
    __syncthreads();

    // Untangle to K[j] = rfft16384(k)[j] / 16384, j = 0..8192.
    {
        const float sc = 1.0f / 16384.0f;
        float2* kc = kw + (size_t)c * KSTRIDE;
        float2* pj_ = ds + SL2(tid);
        const int mb_ = (tid == 0) ? 8192 : (7680 + SL2(512 - tid));
        float s0_, c0_;
        __sincosf(PI_F / 8192.0f * (float)tid, &s0_, &c0_);
        float2 cs = make_float2(c0_, s0_);
#pragma unroll
        for (int r = 0; r < 8; r++) {
            if (tid == 0 && r == 0) {
                float2 W0 = ds[SL2(0)];
                kc[0]    = make_float2((W0.x + W0.y) * sc, 0.f);
                kc[8192] = make_float2((W0.x - W0.y) * sc, 0.f);
                float2 W4 = ds[SL2(4096)];
                kc[4096] = make_float2(W4.x * sc, -W4.y * sc);   // conj(W)*sc
            } else {
                const int j  = tid + (r << 9);
                const int jm = NFFT - j;
                float2 Wj = pj_[r << 9];
                float2 Wm = ds[mb_ - (r << 9)];
                float2 E = (Wj + conjf2(Wm)) * 0.5f;
                float2 D = (Wj - conjf2(Wm)) * 0.5f;
                float2 O = make_float2(D.y, -D.x);               // -i*D
                const float c_ = cs.x, s_ = cs.y;
                float2 tO = cmul(O, make_float2(c_, -s_));
                float2 uO = cmul(conjf2(O), make_float2(c_, s_));
                kc[j]  = (E + tO) * sc;
                kc[jm] = (conjf2(E) - uO) * sc;
            }
            cs = cmul(cs, UE1);
        }
    }
}

// ====== Kernel B: per (b,c): W=FFT(x even/odd) -> untangle*K*tangle -> IFFT -> y ======
__global__ __launch_bounds__(NT2)
void hyena_xconv8(const float* __restrict__ x, const float2* __restrict__ kw,
                  float* __restrict__ y)
{
    __shared__ alignas(16) float2 ds[NFFT];           // 64 KiB -> 2 blocks/CU
    const int bid = blockIdx.x, tid = threadIdx.x;
    const int c = bid >> 1, b = bid & 1;              // adjacent blocks share K row
    const int B_ = tid << 1;
    const float* xp = x + ((size_t)(b * CCH + c)) * LSEQ;
    float*       yp = y + ((size_t)(b * CCH + c)) * LSEQ;

    {   // forward pass0: w[e] = x[2e] + i*x[2e+1]; e >= 4096 zero.
        float2 a0,a1,a2,a3,a4,a5,a6,a7,b0,b1,b2,b3,b4,b5,b6,b7;
        float4 v;
        v = *(const float4*)&xp[(B_ << 1)];
        a0 = make_float2(v.x, v.y); b0 = make_float2(v.z, v.w);
        v = *(const float4*)&xp[(B_ << 1) + 2048];
        a1 = make_float2(v.x, v.y); b1 = make_float2(v.z, v.w);
        v = *(const float4*)&xp[(B_ << 1) + 4096];
        a2 = make_float2(v.x, v.y); b2 = make_float2(v.z, v.w);
        v = *(const float4*)&xp[(B_ << 1) + 6144];
        a3 = make_float2(v.x, v.y); b3 = make_float2(v.z, v.w);
        a4 = a5 = a6 = a7 = b4 = b5 = b6 = b7 = make_float2(0.f, 0.f);
        DFT8AB(-1)
        WR8SEQ
        __syncthreads();
    }
    P8MID(-1, 8,  WD8C,  WD8S)
    P8MID(-1, 64, WD64C, WD64S)
    {   // final radix-16 forward, in place.
        R16_LOAD_TWIDDLE(-1)
        DFT16M(-1, m)
        R16_STORE_LDS
    }
    __syncthreads();

    // Untangle X, multiply by K, tangle to V (pairs (j, N-j) owned per thread).
    {
        const float2* kc = kw + (size_t)c * KSTRIDE;
        float2* pj_ = ds + SL2(tid);
        const int mb_ = (tid == 0) ? 8192 : (7680 + SL2(512 - tid));
        float s0_, c0_;
        __sincosf(PI_F / 8192.0f * (float)tid, &s0_, &c0_);
        float2 cs = make_float2(c0_, s0_);
#pragma unroll
        for (int r = 0; r < 8; r++) {
            if (tid == 0 && r == 0) {
                float2 W0 = ds[SL2(0)];
                float X0 = W0.x + W0.y, XN = W0.x - W0.y;
                float2 K0 = kc[0], KN = kc[8192];
                float2 Z0 = make_float2(X0 * K0.x, X0 * K0.y);
                float2 ZN = make_float2(XN * KN.x, XN * KN.y);
                ds[SL2(0)] = make_float2(Z0.x + ZN.x - (Z0.y - ZN.y),
                                         Z0.y + ZN.y + (Z0.x - ZN.x));
                float2 W4 = ds[SL2(4096)];
                float2 Z4 = cmul(conjf2(W4), kc[4096]);
                ds[SL2(4096)] = make_float2(2.f * Z4.x, -2.f * Z4.y);
            } else {
                const int j  = tid + (r << 9);
                const int jm = NFFT - j;
                float2 Wj = pj_[r << 9];
                float2 Wm = ds[mb_ - (r << 9)];
                float2 E = (Wj + conjf2(Wm)) * 0.5f;
                float2 D = (Wj - conjf2(Wm)) * 0.5f;
                float2 O = make_float2(D.y, -D.x);               // -i*D
                const float c_ = cs.x, s_ = cs.y;
                float2 Xj = E + cmul(O, make_float2(c_, -s_));
                float2 Xm = conjf2(E) - cmul(conjf2(O), make_float2(c_, s_));
                float2 Zj = cmul(Xj, kc[j]);
                float2 Zm = cmul(Xm, kc[jm]);
                float2 P  = Zj + conjf2(Zm);
                float2 Q  = Zj - conjf2(Zm);
                float2 Vj = P + cmul(Q, make_float2(-s_, c_));   // + i e^{i th} Q
                float2 P2 = Zm + conjf2(Zj);
                float2 Q2 = Zm - conjf2(Zj);
                float2 Vm = P2 + cmul(Q2, make_float2(-s_, -c_));
                pj_[r << 9]        = Vj;
                ds[mb_ - (r << 9)] = Vm;
            }
            cs = cmul(cs, UE1);
        }
    }
    __syncthreads();

    // Inverse FFT (unscaled; scaling folded into K).
    P8FIRST_LDS(1)
    P8MID(1, 8,  WD8C,  WD8S)
    P8MID(1, 64, WD64C, WD64S)
    {   // final inverse radix-16: v[n] for n < 4096 only -> y[2n], y[2n+1].
        R16_LOAD_TWIDDLE(1)
        DFT16M(1, m)
        *(float2*)&yp[(tid) << 1]          = m0;
        *(float2*)&yp[(tid +  512) << 1]   = m4;
        *(float2*)&yp[(tid + 1024) << 1]   = m8;
        *(float2*)&yp[(tid + 1536) << 1]   = m12;
        *(float2*)&yp[(tid + 2048) << 1]   = m1;
        *(float2*)&yp[(tid + 2560) << 1]   = m5;
        *(float2*)&yp[(tid + 3072) << 1]   = m9;
        *(float2*)&yp[(tid + 3584) << 1]   = m13;
    }
}

extern "C" void kernel_launch(void* const* d_in, const int* in_sizes, int n_in,
                              void* d_out, int out_size, void* d_ws, size_t ws_size,
                              hipStream_t stream) {
    const float* x    = (const float*)d_in[0];
    const float* k    = (const float*)d_in[1];
    const float* bias = (const float*)d_in[2];
    float* y          = (float*)d_out;
    float2* kw        = (float2*)d_ws;   // 2048 * KSTRIDE float2 (~134 MB)

    hyena_kfft8 <<<dim3(CCH),     dim3(NT2), 0, stream>>>(k, bias, kw);
    hyena_xconv8<<<dim3(2 * CCH), dim3(NT2), 0, stream>>>(x, kw, y);
}